// Round 1
// baseline (245.754 us; speedup 1.0000x reference)
//
#include <hip/hip_runtime.h>
#include <cfloat>

#define TOKENS 32768      // B*L = 16*2048
#define DIM    320
#define K      16
#define NCODE  8192

#define CG  512           // codes per search block
#define TT  512           // tokens per search block (256 thr * 2)
#define NG  (NCODE / CG)  // 16 code groups

// ---------------------------------------------------------------------------
// Kernel 1: projection (B,L,320)x(320,16) -> normalize -> tn, x2.
// Extra blocks compute c2[j] = sum_k cb[j,k]^2.
// Mapping: 16 threads per token (one per k), 16 tokens per 256-thr block.
// ---------------------------------------------------------------------------
__global__ __launch_bounds__(256) void proj_kernel(
    const float* __restrict__ x,    // (32768, 320)
    const float* __restrict__ P,    // (320, 16)
    const float* __restrict__ cb,   // (8192, 16)
    float* __restrict__ tn,         // (32768, 16)
    float* __restrict__ x2o,        // (32768)
    float* __restrict__ c2o)        // (8192)
{
    int bid = blockIdx.x;
    if (bid < TOKENS / 16) {
        int k   = threadIdx.x & 15;
        int tok = bid * 16 + (threadIdx.x >> 4);
        const float* xr = x + (size_t)tok * DIM;
        float acc = 0.f;
        #pragma unroll 8
        for (int d = 0; d < DIM; ++d)
            acc = fmaf(xr[d], P[d * K + k], acc);
        // 16-lane reduce for squared norm
        float ss = acc * acc;
        #pragma unroll
        for (int off = 8; off >= 1; off >>= 1)
            ss += __shfl_xor(ss, off, 16);
        float nrm = fmaxf(sqrtf(ss), 1e-12f);
        float t   = acc / nrm;
        // x2 = sum(tn*tn) after normalization (matches reference)
        float s2 = t * t;
        #pragma unroll
        for (int off = 8; off >= 1; off >>= 1)
            s2 += __shfl_xor(s2, off, 16);
        tn[tok * K + k] = t;
        if (k == 0) x2o[tok] = s2;
    } else {
        int j = (bid - TOKENS / 16) * 256 + threadIdx.x;
        if (j < NCODE) {
            const float* cr = cb + (size_t)j * K;
            float s = 0.f;
            #pragma unroll
            for (int k = 0; k < K; ++k) s = fmaf(cr[k], cr[k], s);
            c2o[j] = s;
        }
    }
}

// ---------------------------------------------------------------------------
// Kernel 2: partial argmin search. Each block: 512 tokens x 512 codes.
// Codes staged in LDS; all lanes read the same code -> broadcast (no bank
// conflicts). 2 tokens per thread amortize the LDS reads.
// d2 = (x2 + c2_j) - 2*dot  (sqrt/clamp omitted: monotone / never active)
// ---------------------------------------------------------------------------
__global__ __launch_bounds__(256) void search_kernel(
    const float* __restrict__ tn,
    const float* __restrict__ x2i,
    const float* __restrict__ cb,
    const float* __restrict__ c2i,
    float* __restrict__ pmin,   // (NG, 32768)
    int*   __restrict__ pidx)   // (NG, 32768)
{
    __shared__ float lc[CG * K];
    __shared__ float lc2[CG];

    int tb = blockIdx.x;           // token tile 0..63
    int gb = blockIdx.y;           // code group 0..NG-1
    int cbase = gb * CG;

    // stage code tile: each thread copies 2 rows of 16 floats
    for (int r = threadIdx.x; r < CG; r += 256) {
        const float4* src = (const float4*)(cb + (size_t)(cbase + r) * K);
        float4* dst = (float4*)(lc + r * K);
        dst[0] = src[0]; dst[1] = src[1]; dst[2] = src[2]; dst[3] = src[3];
        lc2[r] = c2i[cbase + r];
    }
    __syncthreads();

    int t0 = tb * TT + threadIdx.x;
    int t1 = t0 + 256;

    float a0[K], a1[K];
    {
        const float4* p0 = (const float4*)(tn + (size_t)t0 * K);
        const float4* p1 = (const float4*)(tn + (size_t)t1 * K);
        #pragma unroll
        for (int i = 0; i < 4; ++i) {
            float4 v = p0[i];
            a0[4*i] = v.x; a0[4*i+1] = v.y; a0[4*i+2] = v.z; a0[4*i+3] = v.w;
            float4 w = p1[i];
            a1[4*i] = w.x; a1[4*i+1] = w.y; a1[4*i+2] = w.z; a1[4*i+3] = w.w;
        }
    }
    float x20 = x2i[t0], x21 = x2i[t1];

    float mn0 = FLT_MAX, mn1 = FLT_MAX;
    int   i0 = 0, i1 = 0;

    #pragma unroll 2
    for (int j = 0; j < CG; ++j) {
        float cv[K];
        const float4* cj4 = (const float4*)(lc + j * K);
        #pragma unroll
        for (int i = 0; i < 4; ++i) {
            float4 v = cj4[i];
            cv[4*i] = v.x; cv[4*i+1] = v.y; cv[4*i+2] = v.z; cv[4*i+3] = v.w;
        }
        float c2j = lc2[j];
        float d0 = 0.f, d1 = 0.f;
        #pragma unroll
        for (int k = 0; k < K; ++k) {
            d0 = fmaf(a0[k], cv[k], d0);
            d1 = fmaf(a1[k], cv[k], d1);
        }
        // 2*d is exact in fp32, so fmaf(-2,d,s) rounds identically to s-(2*d)
        float e0 = fmaf(-2.f, d0, x20 + c2j);
        float e1 = fmaf(-2.f, d1, x21 + c2j);
        if (e0 < mn0) { mn0 = e0; i0 = cbase + j; }
        if (e1 < mn1) { mn1 = e1; i1 = cbase + j; }
    }

    pmin[(size_t)gb * TOKENS + t0] = mn0;
    pidx[(size_t)gb * TOKENS + t0] = i0;
    pmin[(size_t)gb * TOKENS + t1] = mn1;
    pidx[(size_t)gb * TOKENS + t1] = i1;
}

// ---------------------------------------------------------------------------
// Kernel 3: reduce the NG partials per token (ascending g + strict < keeps
// first-occurrence tie-break, matching argmin).
// ---------------------------------------------------------------------------
__global__ __launch_bounds__(256) void reduce_kernel(
    const float* __restrict__ pmin,
    const int*   __restrict__ pidx,
    int* __restrict__ labels)
{
    int t = blockIdx.x * 256 + threadIdx.x;
    float mn = FLT_MAX;
    int   id = 0;
    #pragma unroll
    for (int g = 0; g < NG; ++g) {
        float v = pmin[(size_t)g * TOKENS + t];
        int   ix = pidx[(size_t)g * TOKENS + t];
        if (v < mn) { mn = v; id = ix; }
    }
    labels[t] = id;
}

extern "C" void kernel_launch(void* const* d_in, const int* in_sizes, int n_in,
                              void* d_out, int out_size, void* d_ws, size_t ws_size,
                              hipStream_t stream) {
    const float* x   = (const float*)d_in[0];  // (16,2048,320)
    const float* P   = (const float*)d_in[1];  // (320,16)
    const float* cbn = (const float*)d_in[2];  // (8192,16)

    float* ws   = (float*)d_ws;
    float* tn   = ws;                       // 524288 floats
    float* x2   = tn + TOKENS * K;          // 32768
    float* c2   = x2 + TOKENS;              // 8192
    float* pmin = c2 + NCODE;               // NG*32768 = 524288
    int*   pidx = (int*)(pmin + (size_t)NG * TOKENS);  // 524288 ints
    int*   labels = (int*)d_out;

    proj_kernel<<<TOKENS / 16 + NCODE / 256, 256, 0, stream>>>(x, P, cbn, tn, x2, c2);
    dim3 sg(TOKENS / TT, NG);
    search_kernel<<<sg, 256, 0, stream>>>(tn, x2, cbn, c2, pmin, pidx);
    reduce_kernel<<<TOKENS / 256, 256, 0, stream>>>(pmin, pidx, labels);
}